// Round 8
// baseline (2687.865 us; speedup 1.0000x reference)
//
#include <hip/hip_runtime.h>
#include <math.h>

#define TB 4
#define TN 1569
#define TC 768
#define TH 12
#define TD 64
#define TP 196
#define TF 8
#define TS 1568
#define TBH 48
#define QSCALE 0.125f

// workspace regions (floats)
#define XTSZ (TB*TS*TF*TC)      // 38,535,168 (154.1 MB)
#define QS   (TBH*TN*TD)        //  4,819,968 (19.3 MB each; q2 overlays qh, y overlays kh)
#define Q2SZ (TB*TS*TC)         //  4,816,896
#define YSZ  (TB*TN*TC)         //  4,819,968
// total ws need: (XTSZ + 3*QS)*4 + 14,155,776 (bf16 weights) + 12,288 (clsout) = 226,148,352 B
#define WS_NEEDED 226148352ULL

#define SPACE_LDS_BYTES ((64*68 + 196*64 + 64*212)*4)  // 121,856 B

typedef unsigned short u16;
typedef unsigned int   u32;
typedef __attribute__((ext_vector_type(8))) short short8v;   // 8 bf16 (4 VGPRs)
typedef __attribute__((ext_vector_type(4))) float float4v;   // 4 fp32 acc

__device__ __forceinline__ float dot4(float4 a, float4 b) {
  return a.x*b.x + a.y*b.y + a.z*b.z + a.w*b.w;
}

// fp32 -> bf16 (RNE) and back, bit-level
__device__ __forceinline__ u16 f2bf(float f) {
  u32 u = __float_as_uint(f);
  u32 r = (u + 0x7fffu + ((u >> 16) & 1u)) >> 16;
  return (u16)r;
}
__device__ __forceinline__ float bf2f(u16 h) {
  return __uint_as_float(((u32)h) << 16);
}

// ---------------------------------------------------------------------------
// Weight pre-pass: W [768][ldw] fp32 (cols 0..767 used) -> W^T hi/lo bf16 [N][768]
// ---------------------------------------------------------------------------
__global__ __launch_bounds__(1024) void transpose_split(const float* __restrict__ W, int ldw,
                                                        u16* __restrict__ Th, u16* __restrict__ Tl) {
  __shared__ float tile[32][33];
  const int tx = threadIdx.x, ty = threadIdx.y;
  const int nb = blockIdx.x * 32, kb = blockIdx.y * 32;
  tile[ty][tx] = W[(size_t)(kb + ty) * ldw + nb + tx];
  __syncthreads();
  const float v = tile[tx][ty];          // = W[kb+tx][nb+ty]
  const int on = nb + ty, ok = kb + tx;  // out[on][ok] = W[ok][on]
  const u16 h = f2bf(v);
  Th[(size_t)on * 768 + ok] = h;
  Tl[(size_t)on * 768 + ok] = f2bf(v - bf2f(h));
}

// ---------------------------------------------------------------------------
// Split-bf16 MFMA GEMM (Ah*Bh + Ah*Bl + Al*Bh, rel err ~2^-17).
// Tile 128x128, BK=32, 4 waves (2x2), wave = 64x64 = 4x4 frags of 16x16x32.
// MODE 0: A=x  -> scatter qh/kh/vh head-major
// MODE 2: A=xt row-remapped (x_diag) -> q2 * scale
// MODE 3: A=y (rows n==0 remapped to Aalt=clsout) -> out + bias
// ---------------------------------------------------------------------------
#define ALD 40   // LDS row stride in ushorts (80 B): 2-way bank aliasing (free)

template<int MODE>
__global__ __launch_bounds__(256) void gemm_mfma(const float* __restrict__ A,
                                                 const float* __restrict__ Aalt,
                                                 const u16* __restrict__ BTh,
                                                 const u16* __restrict__ BTl,
                                                 float* __restrict__ O0,
                                                 float* __restrict__ O1,
                                                 float* __restrict__ O2,
                                                 const float* __restrict__ bias) {
  constexpr int M = (MODE==0) ? (TB*TN) : (MODE==2) ? (TB*TS) : (TB*TN);

  __shared__ u16 Ah[128*ALD];
  __shared__ u16 Al[128*ALD];
  __shared__ u16 Bh[128*ALD];
  __shared__ u16 Bl[128*ALD];

  const int tid  = threadIdx.x;
  const int lane = tid & 63;
  const int wave = tid >> 6;
  const int wr = wave >> 1, wc = wave & 1;
  const int m0 = blockIdx.y * 128, n0 = blockIdx.x * 128;
  const int lrow = lane & 15;          // frag row (A) / frag col (B)
  const int lk   = (lane >> 4) * 8;    // k base within frag

  float4v acc[4][4];
  #pragma unroll
  for (int mi = 0; mi < 4; ++mi)
    #pragma unroll
    for (int ni = 0; ni < 4; ++ni) acc[mi][ni] = (float4v){0.f, 0.f, 0.f, 0.f};

  const int sr = tid >> 1;
  const int sc = (tid & 1) * 16;

  const int agr = m0 + sr;
  const bool avalid = agr < M;
  const float* asrc = nullptr;
  if (avalid) {
    if (MODE == 2)      asrc = A + ((size_t)agr * 8 + (size_t)((agr % TS) / TP)) * 768;
    else if (MODE == 3 && (agr % TN) == 0) asrc = Aalt + (size_t)(agr / TN) * 768;
    else                asrc = A + (size_t)agr * 768;
  }
  const size_t brow_off = (size_t)(n0 + sr) * 768;

  for (int k0 = 0; k0 < 768; k0 += 32) {
    __syncthreads();
    // ---- stage A (fp32 -> hi/lo bf16) ----
    {
      float v[16];
      if (avalid) {
        const float4* ap = reinterpret_cast<const float4*>(asrc + k0 + sc);
        const float4 a0 = ap[0], a1 = ap[1], a2 = ap[2], a3 = ap[3];
        v[0]=a0.x; v[1]=a0.y; v[2]=a0.z; v[3]=a0.w;
        v[4]=a1.x; v[5]=a1.y; v[6]=a1.z; v[7]=a1.w;
        v[8]=a2.x; v[9]=a2.y; v[10]=a2.z; v[11]=a2.w;
        v[12]=a3.x; v[13]=a3.y; v[14]=a3.z; v[15]=a3.w;
      } else {
        #pragma unroll
        for (int j = 0; j < 16; ++j) v[j] = 0.f;
      }
      u32 hw[8], lw[8];
      #pragma unroll
      for (int j = 0; j < 8; ++j) {
        const u16 h0 = f2bf(v[2*j]),   h1 = f2bf(v[2*j+1]);
        const u16 l0 = f2bf(v[2*j]   - bf2f(h0));
        const u16 l1 = f2bf(v[2*j+1] - bf2f(h1));
        hw[j] = (u32)h0 | ((u32)h1 << 16);
        lw[j] = (u32)l0 | ((u32)l1 << 16);
      }
      *reinterpret_cast<uint4*>(&Ah[sr*ALD + sc])     = make_uint4(hw[0],hw[1],hw[2],hw[3]);
      *reinterpret_cast<uint4*>(&Ah[sr*ALD + sc + 8]) = make_uint4(hw[4],hw[5],hw[6],hw[7]);
      *reinterpret_cast<uint4*>(&Al[sr*ALD + sc])     = make_uint4(lw[0],lw[1],lw[2],lw[3]);
      *reinterpret_cast<uint4*>(&Al[sr*ALD + sc + 8]) = make_uint4(lw[4],lw[5],lw[6],lw[7]);
    }
    // ---- stage B (bf16 hi/lo, [N][768]) ----
    {
      const u16* gh = BTh + brow_off + k0 + sc;
      const u16* gl = BTl + brow_off + k0 + sc;
      const uint4 h0 = *reinterpret_cast<const uint4*>(gh);
      const uint4 h1 = *reinterpret_cast<const uint4*>(gh + 8);
      const uint4 l0 = *reinterpret_cast<const uint4*>(gl);
      const uint4 l1 = *reinterpret_cast<const uint4*>(gl + 8);
      *reinterpret_cast<uint4*>(&Bh[sr*ALD + sc])     = h0;
      *reinterpret_cast<uint4*>(&Bh[sr*ALD + sc + 8]) = h1;
      *reinterpret_cast<uint4*>(&Bl[sr*ALD + sc])     = l0;
      *reinterpret_cast<uint4*>(&Bl[sr*ALD + sc + 8]) = l1;
    }
    __syncthreads();
    // ---- compute: 48 MFMA per wave per K-step ----
    short8v ahf[4], alf[4];
    #pragma unroll
    for (int mi = 0; mi < 4; ++mi) {
      const int r = (wr*64 + mi*16 + lrow)*ALD + lk;
      ahf[mi] = *reinterpret_cast<const short8v*>(&Ah[r]);
      alf[mi] = *reinterpret_cast<const short8v*>(&Al[r]);
    }
    #pragma unroll
    for (int ni = 0; ni < 4; ++ni) {
      const int r = (wc*64 + ni*16 + lrow)*ALD + lk;
      const short8v bhf = *reinterpret_cast<const short8v*>(&Bh[r]);
      const short8v blf = *reinterpret_cast<const short8v*>(&Bl[r]);
      #pragma unroll
      for (int mi = 0; mi < 4; ++mi) {
        acc[mi][ni] = __builtin_amdgcn_mfma_f32_16x16x32_bf16(ahf[mi], bhf, acc[mi][ni], 0, 0, 0);
        acc[mi][ni] = __builtin_amdgcn_mfma_f32_16x16x32_bf16(ahf[mi], blf, acc[mi][ni], 0, 0, 0);
        acc[mi][ni] = __builtin_amdgcn_mfma_f32_16x16x32_bf16(alf[mi], bhf, acc[mi][ni], 0, 0, 0);
      }
    }
  }

  // ---- epilogue: C/D map col=lane&15, row=(lane>>4)*4+reg ----
  const int rbase = (lane >> 4) * 4;
  #pragma unroll
  for (int mi = 0; mi < 4; ++mi) {
    #pragma unroll
    for (int ni = 0; ni < 4; ++ni) {
      #pragma unroll
      for (int rg = 0; rg < 4; ++rg) {
        const int gr = m0 + wr*64 + mi*16 + rbase + rg;
        if (gr >= M) continue;
        const int gc = n0 + wc*64 + ni*16 + lrow;
        const float val = acc[mi][ni][rg];
        if (MODE == 0) {
          const int b = gr / TN, n = gr % TN;
          const int which = gc / 768, rem = gc - which*768;
          const int hh = rem >> 6, dd = rem & 63;
          float* dst = (which == 0) ? O0 : (which == 1) ? O1 : O2;
          dst[((size_t)(b*TH + hh)*TN + n)*64 + dd] = val;
        } else if (MODE == 2) {
          O0[(size_t)gr*768 + gc] = val * QSCALE;
        } else {
          O0[(size_t)gr*768 + gc] = val + bias[gc];
        }
      }
    }
  }
}

// ---------------------------------------------------------------------------
// cls-token attention: one block per (b,h); writes clsout[b*768 + h*64 + d].
// ---------------------------------------------------------------------------
__global__ __launch_bounds__(256) void cls_attn(const float* __restrict__ qg,
                                                const float* __restrict__ kg,
                                                const float* __restrict__ vg,
                                                float* __restrict__ clsout) {
  __shared__ float q0s[64];
  __shared__ float lg[TN];
  __shared__ float red[256];
  const int tid = threadIdx.x;
  const int bh = blockIdx.x;

  if (tid < 16) {
    float4 v = ((const float4*)qg)[(bh*TN + 0)*16 + tid];
    v.x *= QSCALE; v.y *= QSCALE; v.z *= QSCALE; v.w *= QSCALE;
    ((float4*)q0s)[tid] = v;
  }
  __syncthreads();
  for (int n = tid; n < TN; n += 256) {
    float s = 0.f;
    #pragma unroll
    for (int kc = 0; kc < 16; ++kc)
      s += dot4(((const float4*)kg)[(bh*TN + n)*16 + kc], ((float4*)q0s)[kc]);
    lg[n] = s;
  }
  __syncthreads();
  float mx = -1e30f;
  for (int n = tid; n < TN; n += 256) mx = fmaxf(mx, lg[n]);
  red[tid] = mx; __syncthreads();
  for (int st = 128; st > 0; st >>= 1) {
    if (tid < st) red[tid] = fmaxf(red[tid], red[tid+st]);
    __syncthreads();
  }
  const float m = red[0];
  __syncthreads();
  float ls = 0.f;
  for (int n = tid; n < TN; n += 256) { const float e = __expf(lg[n] - m); lg[n] = e; ls += e; }
  red[tid] = ls; __syncthreads();
  for (int st = 128; st > 0; st >>= 1) {
    if (tid < st) red[tid] += red[tid+st];
    __syncthreads();
  }
  const float rl = 1.f / red[0];
  __syncthreads();
  const int d = tid & 63, g = tid >> 6;
  float part = 0.f;
  for (int n = g; n < TN; n += 4) part += lg[n] * vg[(bh*TN + n)*64 + d];
  red[tid] = part; __syncthreads();
  if (tid < 64) {
    const int b = bh / TH, h = bh % TH;
    clsout[b*768 + h*64 + d] = (red[d] + red[64+d] + red[128+d] + red[192+d]) * rl;
  }
}

// ---------------------------------------------------------------------------
// Space attention: block = (bh, 64-query tile); loop f=0..7. (unchanged)
// ---------------------------------------------------------------------------
__global__ __launch_bounds__(256) void space_attn(const float* __restrict__ qg,
                                                  const float* __restrict__ kg,
                                                  const float* __restrict__ vg,
                                                  float* __restrict__ xt) {
  extern __shared__ __align__(16) float sm[];
  float*  Qs = sm;                          // 64 x 68 (scaled q)
  float4* KV = (float4*)(sm + 64*68);       // 196 x 16 float4 (K swizzled / V linear)
  float*  Pm = sm + 64*68 + 196*64;         // 64 x 212 logits/weights

  const int tid = threadIdx.x;
  const int tx = tid & 15, ty = tid >> 4;
  const int bh = blockIdx.y;
  const int qbase = blockIdx.x * 64;
  const int b = bh / TH, h = bh % TH;

  for (int id = tid; id < 64*16; id += 256) {
    const int qi = id >> 4, kc = id & 15;
    const int qgl = qbase + qi;
    float4 v = make_float4(0.f, 0.f, 0.f, 0.f);
    if (qgl < TS) {
      v = ((const float4*)qg)[(bh*TN + 1 + qgl)*16 + kc];
      v.x *= QSCALE; v.y *= QSCALE; v.z *= QSCALE; v.w *= QSCALE;
    }
    *reinterpret_cast<float4*>(Qs + qi*68 + 4*kc) = v;
  }

  for (int f = 0; f < TF; ++f) {
    __syncthreads();
    for (int id = tid; id < 196*16; id += 256) {
      const int j = id >> 4, kc = id & 15;
      KV[j*16 + (kc ^ ((j >> 2) & 15))] =
          ((const float4*)kg)[(bh*TN + 1 + f*TP + j)*16 + kc];
    }
    __syncthreads();

    for (int pass = 0; pass < 4; ++pass) {
      float a[4][4] = {};
      const int jb = pass*64 + 4*tx;
      #pragma unroll 4
      for (int kc = 0; kc < 16; ++kc) {
        float4 qv[4];
        #pragma unroll
        for (int i = 0; i < 4; ++i)
          qv[i] = *reinterpret_cast<const float4*>(Qs + (4*ty+i)*68 + 4*kc);
        #pragma unroll
        for (int jj = 0; jj < 4; ++jj) {
          int jr = jb + jj; if (jr > 195) jr = 195;
          const float4 kv = KV[jr*16 + (kc ^ ((jr >> 2) & 15))];
          #pragma unroll
          for (int i = 0; i < 4; ++i) a[i][jj] += dot4(qv[i], kv);
        }
      }
      #pragma unroll
      for (int i = 0; i < 4; ++i)
        #pragma unroll
        for (int jj = 0; jj < 4; ++jj) {
          const int j = jb + jj;
          if (j < 196) Pm[(4*ty+i)*212 + j] = a[i][jj];
        }
    }
    __syncthreads();

    for (int id = tid; id < 196*16; id += 256) {
      const int j = id >> 4, kc = id & 15;
      KV[j*16 + kc] = ((const float4*)vg)[(bh*TN + 1 + f*TP + j)*16 + kc];
    }
    {
      const int q = tid >> 2, g = tid & 3;
      float* row = Pm + q*212;
      float mx = -1e30f;
      for (int mm = 0; mm < 49; ++mm) mx = fmaxf(mx, row[g + 4*mm]);
      mx = fmaxf(mx, __shfl_xor(mx, 1, 4));
      mx = fmaxf(mx, __shfl_xor(mx, 2, 4));
      float l = 0.f;
      for (int mm = 0; mm < 49; ++mm) {
        const float e = __expf(row[g + 4*mm] - mx);
        row[g + 4*mm] = e; l += e;
      }
      l += __shfl_xor(l, 1, 4);
      l += __shfl_xor(l, 2, 4);
      const float rl = 1.f / l;
      for (int mm = 0; mm < 49; ++mm) row[g + 4*mm] *= rl;
    }
    __syncthreads();

    float oo[4][4] = {};
    for (int j4 = 0; j4 < 49; ++j4) {
      float pr[4][4];
      #pragma unroll
      for (int i = 0; i < 4; ++i)
        *reinterpret_cast<float4*>(pr[i]) =
            *reinterpret_cast<const float4*>(Pm + (4*ty+i)*212 + 4*j4);
      #pragma unroll
      for (int jj = 0; jj < 4; ++jj) {
        const float4 vv = KV[(4*j4+jj)*16 + tx];
        #pragma unroll
        for (int i = 0; i < 4; ++i) {
          oo[i][0] += pr[i][jj]*vv.x;
          oo[i][1] += pr[i][jj]*vv.y;
          oo[i][2] += pr[i][jj]*vv.z;
          oo[i][3] += pr[i][jj]*vv.w;
        }
      }
    }
    #pragma unroll
    for (int i = 0; i < 4; ++i) {
      const int s = qbase + 4*ty + i;
      if (s < TS) {
        *reinterpret_cast<float4*>(xt + ((size_t)(b*TS + s)*TF + f)*TC + h*64 + 4*tx) =
            make_float4(oo[i][0], oo[i][1], oo[i][2], oo[i][3]);
      }
    }
  }
}

// ---------------------------------------------------------------------------
// Second stage per (b,s), k2-free:
//   u[h][k] = sum_d w_kvT[h*64+d][k] * q2[h*64+d]        (w_kvT from L2, hi+lo)
//   logit[h][f] = sum_k xt[b,s,f,k] * u[h][k]; softmax_f -> attn2
//   y[b,1+s] = sum_f attn2 * xt[b,s,f,:]
// ---------------------------------------------------------------------------
#define USTRIDE 772   // 772%32=4 -> h-rows staggered 4 banks apart (conflict-free reads)

__global__ __launch_bounds__(256) void second_stage(const float* __restrict__ q2,
                                                    const u16* __restrict__ wkvTh,
                                                    const u16* __restrict__ wkvTl,
                                                    const float* __restrict__ xt,
                                                    float* __restrict__ y,
                                                    float* __restrict__ attn2) {
  __shared__ float q2s[768];
  __shared__ float us[12*USTRIDE];
  __shared__ float a2s[96];
  const int tid = threadIdx.x;
  const int bs = blockIdx.x;
  const int b = bs / TS, s = bs - b*TS;

  for (int id = tid; id < 192; id += 256)
    ((float4*)q2s)[id] = ((const float4*)q2)[(size_t)bs*192 + id];
  __syncthreads();

  // u-phase: 9216 outputs, coalesced over k (256|768 -> wave-uniform h)
  for (int idx = tid; idx < 9216; idx += 256) {
    const int h = idx / 768, k = idx - h*768;
    const u16* ph = wkvTh + (size_t)(h*64)*768 + k;
    const u16* pl = wkvTl + (size_t)(h*64)*768 + k;
    const float* qq = q2s + h*64;
    float acc = 0.f;
    #pragma unroll 8
    for (int d = 0; d < 64; ++d)
      acc += (bf2f(ph[(size_t)d*768]) + bf2f(pl[(size_t)d*768])) * qq[d];
    us[h*USTRIDE + k] = acc;
  }
  __syncthreads();

  // logits + softmax + attn2 (96 task-threads, 8-lane shfl groups)
  if (tid < 96) {
    const int h = tid >> 3, f = tid & 7;
    const float4* xrow = (const float4*)(xt + (size_t)bs*(TF*TC) + f*TC);
    const float*  urow = us + h*USTRIDE;
    float lgt = 0.f;
    for (int k4 = 0; k4 < 192; ++k4)
      lgt += dot4(xrow[k4], *reinterpret_cast<const float4*>(urow + 4*k4));
    float mx = lgt;
    mx = fmaxf(mx, __shfl_xor(mx, 1, 8));
    mx = fmaxf(mx, __shfl_xor(mx, 2, 8));
    mx = fmaxf(mx, __shfl_xor(mx, 4, 8));
    const float e = __expf(lgt - mx);
    float sum = e;
    sum += __shfl_xor(sum, 1, 8);
    sum += __shfl_xor(sum, 2, 8);
    sum += __shfl_xor(sum, 4, 8);
    const float a = e / sum;
    attn2[((size_t)(b*TH + h)*TS + s)*8 + f] = a;
    a2s[tid] = a;
  }
  __syncthreads();

  const float* xrow0 = xt + (size_t)bs*(TF*TC);
  for (int c = tid; c < 768; c += 256) {
    const int h = c >> 6;
    float o = 0.f;
    #pragma unroll
    for (int f = 0; f < 8; ++f) o += a2s[h*8 + f] * xrow0[f*768 + c];
    y[((size_t)b*TN + 1 + s)*TC + c] = o;
  }
}

// ---------------------------------------------------------------------------
extern "C" void kernel_launch(void* const* d_in, const int* in_sizes, int n_in,
                              void* d_out, int out_size, void* d_ws, size_t ws_size,
                              hipStream_t stream) {
  if (ws_size < WS_NEEDED) return;   // diagnostic guard: clean fail, not a fault

  const float* x      = (const float*)d_in[0];
  const float* w_qkv  = (const float*)d_in[1];
  const float* w_q    = (const float*)d_in[2];
  const float* w_kv   = (const float*)d_in[3];
  const float* w_proj = (const float*)d_in[4];
  const float* b_proj = (const float*)d_in[5];

  float* ws = (float*)d_ws;
  float* xt = ws;                 // [0, XTSZ)
  float* qh = xt + XTSZ;          // later reused as q2
  float* kh = qh + QS;            // later reused as y
  float* vh = kh + QS;
  float* q2 = qh;                 // overlay (qkv dead by then)
  float* y  = kh;                 // overlay (rows 1.. only; row 0 via clsout)

  u16* wp = (u16*)(vh + QS);
  u16* wqkvT_h = wp;  wp += 2304*768;
  u16* wqkvT_l = wp;  wp += 2304*768;
  u16* wkvT_h  = wp;  wp += 768*768;
  u16* wkvT_l  = wp;  wp += 768*768;
  u16* wqT_h   = wp;  wp += 768*768;
  u16* wqT_l   = wp;  wp += 768*768;
  u16* wprojT_h = wp; wp += 768*768;
  u16* wprojT_l = wp; wp += 768*768;
  float* clsout = (float*)wp;     // 3072 floats

  float* outp  = (float*)d_out;
  float* attn2 = outp + YSZ;

  hipFuncSetAttribute(reinterpret_cast<const void*>(space_attn),
                      hipFuncAttributeMaxDynamicSharedMemorySize, SPACE_LDS_BYTES);

  const dim3 blk(256);
  const dim3 tblk(32, 32);
  // 0. weight pre-pass: transpose + hi/lo split (bf16), [N][768]
  transpose_split<<<dim3(72, 24), tblk, 0, stream>>>(w_qkv, 2304, wqkvT_h, wqkvT_l);
  transpose_split<<<dim3(24, 24), tblk, 0, stream>>>(w_kv, 1536, wkvT_h, wkvT_l);
  transpose_split<<<dim3(24, 24), tblk, 0, stream>>>(w_q,   768, wqT_h,  wqT_l);
  transpose_split<<<dim3(24, 24), tblk, 0, stream>>>(w_proj,768, wprojT_h, wprojT_l);
  // 1. qkv projection + head scatter
  gemm_mfma<0><<<dim3(18, 50), blk, 0, stream>>>(x, nullptr, wqkvT_h, wqkvT_l, qh, kh, vh, nullptr);
  // 2. space attention -> xt
  space_attn<<<dim3(25, 48), blk, SPACE_LDS_BYTES, stream>>>(qh, kh, vh, xt);
  // 3. cls attention -> clsout (after space_attn; before q2/y overlays)
  cls_attn<<<dim3(48), blk, 0, stream>>>(qh, kh, vh, clsout);
  // 4. q2 = x_diag @ w_q * scale   (q2 overlays qh)
  gemm_mfma<2><<<dim3(6, 49), blk, 0, stream>>>(xt, nullptr, wqT_h, wqT_l, q2, nullptr, nullptr, nullptr);
  // 5. attn2 (output) + out rows -> y (overlays kh), k2-free u-trick
  second_stage<<<dim3(TB*TS), blk, 0, stream>>>(q2, wkvT_h, wkvT_l, xt, y, attn2);
  // 6. final projection + bias -> d_out (row 0 of A remapped to clsout)
  gemm_mfma<3><<<dim3(6, 50), blk, 0, stream>>>(y, clsout, wprojT_h, wprojT_l, outp, nullptr, nullptr, b_proj);
}

// Round 9
// 1974.384 us; speedup vs baseline: 1.3614x; 1.3614x over previous
//
#include <hip/hip_runtime.h>
#include <math.h>

#define TB 4
#define TN 1569
#define TC 768
#define TH 12
#define TD 64
#define TP 196
#define TF 8
#define TS 1568
#define TBH 48
#define QSCALE 0.125f

// workspace regions (floats)
#define XTSZ (TB*TS*TF*TC)      // 38,535,168 (154.1 MB)
#define QS   (TBH*TN*TD)        //  4,819,968 (19.3 MB each; q2 overlays qh, y overlays kh)
#define Q2SZ (TB*TS*TC)         //  4,816,896
#define YSZ  (TB*TN*TC)         //  4,819,968
#define WS_NEEDED 226148352ULL

// space_attn MFMA LDS (u16 units): Qh/Ql 4096 each, KV union 16384 each, Ph/Pl 16384 each
#define SPACE_LDS_BYTES 147456

typedef unsigned short u16;
typedef unsigned int   u32;
typedef __attribute__((ext_vector_type(8))) short short8v;   // 8 bf16 (4 VGPRs)
typedef __attribute__((ext_vector_type(4))) float float4v;   // 4 fp32 acc

__device__ __forceinline__ float dot4(float4 a, float4 b) {
  return a.x*b.x + a.y*b.y + a.z*b.z + a.w*b.w;
}

// fp32 -> bf16 (RNE) and back, bit-level
__device__ __forceinline__ u16 f2bf(float f) {
  u32 u = __float_as_uint(f);
  u32 r = (u + 0x7fffu + ((u >> 16) & 1u)) >> 16;
  return (u16)r;
}
__device__ __forceinline__ float bf2f(u16 h) {
  return __uint_as_float(((u32)h) << 16);
}
__device__ __forceinline__ void split2(float a, float b, u32& hw, u32& lw) {
  const u16 h0 = f2bf(a), h1 = f2bf(b);
  const u16 l0 = f2bf(a - bf2f(h0)), l1 = f2bf(b - bf2f(h1));
  hw = (u32)h0 | ((u32)h1 << 16);
  lw = (u32)l0 | ((u32)l1 << 16);
}

// ---------------------------------------------------------------------------
// Weight pre-pass: W [768][ldw] fp32 -> W^T hi/lo bf16 [N][768]
// ---------------------------------------------------------------------------
__global__ __launch_bounds__(1024) void transpose_split(const float* __restrict__ W, int ldw,
                                                        u16* __restrict__ Th, u16* __restrict__ Tl) {
  __shared__ float tile[32][33];
  const int tx = threadIdx.x, ty = threadIdx.y;
  const int nb = blockIdx.x * 32, kb = blockIdx.y * 32;
  tile[ty][tx] = W[(size_t)(kb + ty) * ldw + nb + tx];
  __syncthreads();
  const float v = tile[tx][ty];
  const int on = nb + ty, ok = kb + tx;
  const u16 h = f2bf(v);
  Th[(size_t)on * 768 + ok] = h;
  Tl[(size_t)on * 768 + ok] = f2bf(v - bf2f(h));
}

// ---------------------------------------------------------------------------
// Split-bf16 MFMA GEMM (unchanged from round 8; HW-validated)
// ---------------------------------------------------------------------------
#define ALD 40

template<int MODE>
__global__ __launch_bounds__(256) void gemm_mfma(const float* __restrict__ A,
                                                 const float* __restrict__ Aalt,
                                                 const u16* __restrict__ BTh,
                                                 const u16* __restrict__ BTl,
                                                 float* __restrict__ O0,
                                                 float* __restrict__ O1,
                                                 float* __restrict__ O2,
                                                 const float* __restrict__ bias) {
  constexpr int M = (MODE==0) ? (TB*TN) : (MODE==2) ? (TB*TS) : (TB*TN);

  __shared__ u16 Ah[128*ALD];
  __shared__ u16 Al[128*ALD];
  __shared__ u16 Bh[128*ALD];
  __shared__ u16 Bl[128*ALD];

  const int tid  = threadIdx.x;
  const int lane = tid & 63;
  const int wave = tid >> 6;
  const int wr = wave >> 1, wc = wave & 1;
  const int m0 = blockIdx.y * 128, n0 = blockIdx.x * 128;
  const int lrow = lane & 15;
  const int lk   = (lane >> 4) * 8;

  float4v acc[4][4];
  #pragma unroll
  for (int mi = 0; mi < 4; ++mi)
    #pragma unroll
    for (int ni = 0; ni < 4; ++ni) acc[mi][ni] = (float4v){0.f, 0.f, 0.f, 0.f};

  const int sr = tid >> 1;
  const int sc = (tid & 1) * 16;

  const int agr = m0 + sr;
  const bool avalid = agr < M;
  const float* asrc = nullptr;
  if (avalid) {
    if (MODE == 2)      asrc = A + ((size_t)agr * 8 + (size_t)((agr % TS) / TP)) * 768;
    else if (MODE == 3 && (agr % TN) == 0) asrc = Aalt + (size_t)(agr / TN) * 768;
    else                asrc = A + (size_t)agr * 768;
  }
  const size_t brow_off = (size_t)(n0 + sr) * 768;

  for (int k0 = 0; k0 < 768; k0 += 32) {
    __syncthreads();
    {
      float v[16];
      if (avalid) {
        const float4* ap = reinterpret_cast<const float4*>(asrc + k0 + sc);
        const float4 a0 = ap[0], a1 = ap[1], a2 = ap[2], a3 = ap[3];
        v[0]=a0.x; v[1]=a0.y; v[2]=a0.z; v[3]=a0.w;
        v[4]=a1.x; v[5]=a1.y; v[6]=a1.z; v[7]=a1.w;
        v[8]=a2.x; v[9]=a2.y; v[10]=a2.z; v[11]=a2.w;
        v[12]=a3.x; v[13]=a3.y; v[14]=a3.z; v[15]=a3.w;
      } else {
        #pragma unroll
        for (int j = 0; j < 16; ++j) v[j] = 0.f;
      }
      u32 hw[8], lw[8];
      #pragma unroll
      for (int j = 0; j < 8; ++j) split2(v[2*j], v[2*j+1], hw[j], lw[j]);
      *reinterpret_cast<uint4*>(&Ah[sr*ALD + sc])     = make_uint4(hw[0],hw[1],hw[2],hw[3]);
      *reinterpret_cast<uint4*>(&Ah[sr*ALD + sc + 8]) = make_uint4(hw[4],hw[5],hw[6],hw[7]);
      *reinterpret_cast<uint4*>(&Al[sr*ALD + sc])     = make_uint4(lw[0],lw[1],lw[2],lw[3]);
      *reinterpret_cast<uint4*>(&Al[sr*ALD + sc + 8]) = make_uint4(lw[4],lw[5],lw[6],lw[7]);
    }
    {
      const u16* gh = BTh + brow_off + k0 + sc;
      const u16* gl = BTl + brow_off + k0 + sc;
      const uint4 h0 = *reinterpret_cast<const uint4*>(gh);
      const uint4 h1 = *reinterpret_cast<const uint4*>(gh + 8);
      const uint4 l0 = *reinterpret_cast<const uint4*>(gl);
      const uint4 l1 = *reinterpret_cast<const uint4*>(gl + 8);
      *reinterpret_cast<uint4*>(&Bh[sr*ALD + sc])     = h0;
      *reinterpret_cast<uint4*>(&Bh[sr*ALD + sc + 8]) = h1;
      *reinterpret_cast<uint4*>(&Bl[sr*ALD + sc])     = l0;
      *reinterpret_cast<uint4*>(&Bl[sr*ALD + sc + 8]) = l1;
    }
    __syncthreads();
    short8v ahf[4], alf[4];
    #pragma unroll
    for (int mi = 0; mi < 4; ++mi) {
      const int r = (wr*64 + mi*16 + lrow)*ALD + lk;
      ahf[mi] = *reinterpret_cast<const short8v*>(&Ah[r]);
      alf[mi] = *reinterpret_cast<const short8v*>(&Al[r]);
    }
    #pragma unroll
    for (int ni = 0; ni < 4; ++ni) {
      const int r = (wc*64 + ni*16 + lrow)*ALD + lk;
      const short8v bhf = *reinterpret_cast<const short8v*>(&Bh[r]);
      const short8v blf = *reinterpret_cast<const short8v*>(&Bl[r]);
      #pragma unroll
      for (int mi = 0; mi < 4; ++mi) {
        acc[mi][ni] = __builtin_amdgcn_mfma_f32_16x16x32_bf16(ahf[mi], bhf, acc[mi][ni], 0, 0, 0);
        acc[mi][ni] = __builtin_amdgcn_mfma_f32_16x16x32_bf16(ahf[mi], blf, acc[mi][ni], 0, 0, 0);
        acc[mi][ni] = __builtin_amdgcn_mfma_f32_16x16x32_bf16(alf[mi], bhf, acc[mi][ni], 0, 0, 0);
      }
    }
  }

  const int rbase = (lane >> 4) * 4;
  #pragma unroll
  for (int mi = 0; mi < 4; ++mi) {
    #pragma unroll
    for (int ni = 0; ni < 4; ++ni) {
      #pragma unroll
      for (int rg = 0; rg < 4; ++rg) {
        const int gr = m0 + wr*64 + mi*16 + rbase + rg;
        if (gr >= M) continue;
        const int gc = n0 + wc*64 + ni*16 + lrow;
        const float val = acc[mi][ni][rg];
        if (MODE == 0) {
          const int b = gr / TN, n = gr % TN;
          const int which = gc / 768, rem = gc - which*768;
          const int hh = rem >> 6, dd = rem & 63;
          float* dst = (which == 0) ? O0 : (which == 1) ? O1 : O2;
          dst[((size_t)(b*TH + hh)*TN + n)*64 + dd] = val;
        } else if (MODE == 2) {
          O0[(size_t)gr*768 + gc] = val * QSCALE;
        } else {
          O0[(size_t)gr*768 + gc] = val + bias[gc];
        }
      }
    }
  }
}

// ---------------------------------------------------------------------------
// cls-token attention (unchanged): writes clsout[b*768 + h*64 + d].
// ---------------------------------------------------------------------------
__global__ __launch_bounds__(256) void cls_attn(const float* __restrict__ qg,
                                                const float* __restrict__ kg,
                                                const float* __restrict__ vg,
                                                float* __restrict__ clsout) {
  __shared__ float q0s[64];
  __shared__ float lg[TN];
  __shared__ float red[256];
  const int tid = threadIdx.x;
  const int bh = blockIdx.x;

  if (tid < 16) {
    float4 v = ((const float4*)qg)[(bh*TN + 0)*16 + tid];
    v.x *= QSCALE; v.y *= QSCALE; v.z *= QSCALE; v.w *= QSCALE;
    ((float4*)q0s)[tid] = v;
  }
  __syncthreads();
  for (int n = tid; n < TN; n += 256) {
    float s = 0.f;
    #pragma unroll
    for (int kc = 0; kc < 16; ++kc)
      s += dot4(((const float4*)kg)[(bh*TN + n)*16 + kc], ((float4*)q0s)[kc]);
    lg[n] = s;
  }
  __syncthreads();
  float mx = -1e30f;
  for (int n = tid; n < TN; n += 256) mx = fmaxf(mx, lg[n]);
  red[tid] = mx; __syncthreads();
  for (int st = 128; st > 0; st >>= 1) {
    if (tid < st) red[tid] = fmaxf(red[tid], red[tid+st]);
    __syncthreads();
  }
  const float m = red[0];
  __syncthreads();
  float ls = 0.f;
  for (int n = tid; n < TN; n += 256) { const float e = __expf(lg[n] - m); lg[n] = e; ls += e; }
  red[tid] = ls; __syncthreads();
  for (int st = 128; st > 0; st >>= 1) {
    if (tid < st) red[tid] += red[tid+st];
    __syncthreads();
  }
  const float rl = 1.f / red[0];
  __syncthreads();
  const int d = tid & 63, g = tid >> 6;
  float part = 0.f;
  for (int n = g; n < TN; n += 4) part += lg[n] * vg[(bh*TN + n)*64 + d];
  red[tid] = part; __syncthreads();
  if (tid < 64) {
    const int b = bh / TH, h = bh % TH;
    clsout[b*768 + h*64 + d] = (red[d] + red[64+d] + red[128+d] + red[192+d]) * rl;
  }
}

// ---------------------------------------------------------------------------
// Space attention, MFMA version. Block = (qtile of 64 q-rows, bh); f-loop.
// All LDS tiles split-bf16 (hi/lo) with 16B-slot XOR swizzle (slot ^= row&7).
// Per f: stage K [208][64] -> S = Q*K^T (13 acc frags/wave) -> reg softmax
// (shfl over 16-lane group) -> P split to LDS [64][256] -> stage V^T [64][256]
// (overlays K) -> O = P*V^T via MFMA -> scalar-coalesced store to xt.
// ---------------------------------------------------------------------------
__global__ __launch_bounds__(256) void space_attn(const float* __restrict__ qg,
                                                  const float* __restrict__ kg,
                                                  const float* __restrict__ vg,
                                                  float* __restrict__ xt) {
  extern __shared__ __align__(16) u16 sm[];
  u16* Qh  = sm;            // [64][64]
  u16* Ql  = sm + 4096;
  u16* KVh = sm + 8192;     // K [208][64] | VT [64][256] (union, 16384 u16)
  u16* KVl = sm + 24576;
  u16* Ph  = sm + 40960;    // [64][256]
  u16* Pl  = sm + 57344;

  const int tid  = threadIdx.x;
  const int lane = tid & 63;
  const int wv   = tid >> 6;
  const int bh = blockIdx.y;
  const int qbase = blockIdx.x * 64;
  const int b = bh / TH, h = bh % TH;
  const int l15 = lane & 15;
  const int lg4 = lane >> 4;
  const int xk  = l15 & 7;          // row&7 for all frag reads (tile base ≡ 0 mod 8)

  // ---- zero P pad cols n in [196,224) (never rewritten) ----
  for (int id = tid; id < 1792; id += 256) {
    const int q = id / 28, n = 196 + id % 28;
    const int ad = q*256 + (((n>>3) ^ (q&7))<<3) + (n&7);
    Ph[ad] = 0; Pl[ad] = 0;
  }

  // ---- stage Q (once): row r = tid>>2, chunk c = tid&3 (16 cols) ----
  {
    const int r = tid >> 2, c = tid & 3;
    const int qglob = qbase + r;
    float v[16];
    if (qglob < TS) {
      const float4* ap = (const float4*)(qg + ((size_t)bh*TN + 1 + qglob)*64 + c*16);
      const float4 a0 = ap[0], a1 = ap[1], a2 = ap[2], a3 = ap[3];
      v[0]=a0.x; v[1]=a0.y; v[2]=a0.z; v[3]=a0.w;
      v[4]=a1.x; v[5]=a1.y; v[6]=a1.z; v[7]=a1.w;
      v[8]=a2.x; v[9]=a2.y; v[10]=a2.z; v[11]=a2.w;
      v[12]=a3.x; v[13]=a3.y; v[14]=a3.z; v[15]=a3.w;
      #pragma unroll
      for (int j = 0; j < 16; ++j) v[j] *= QSCALE;
    } else {
      #pragma unroll
      for (int j = 0; j < 16; ++j) v[j] = 0.f;
    }
    u32 hw[8], lw[8];
    #pragma unroll
    for (int j = 0; j < 8; ++j) split2(v[2*j], v[2*j+1], hw[j], lw[j]);
    const int rb = r*64, x = r & 7;
    *(uint4*)(Qh + rb + (((2*c)   ^ x)<<3)) = make_uint4(hw[0],hw[1],hw[2],hw[3]);
    *(uint4*)(Qh + rb + (((2*c+1) ^ x)<<3)) = make_uint4(hw[4],hw[5],hw[6],hw[7]);
    *(uint4*)(Ql + rb + (((2*c)   ^ x)<<3)) = make_uint4(lw[0],lw[1],lw[2],lw[3]);
    *(uint4*)(Ql + rb + (((2*c+1) ^ x)<<3)) = make_uint4(lw[4],lw[5],lw[6],lw[7]);
  }
  __syncthreads();

  // ---- hoist Q A-frags to registers (f-invariant) ----
  short8v qfh[2], qfl[2];
  {
    const int rb = (wv*16 + l15) * 64;
    #pragma unroll
    for (int ks = 0; ks < 2; ++ks) {
      const int ad = rb + (((ks*4 + lg4) ^ xk) << 3);
      qfh[ks] = *(const short8v*)(Qh + ad);
      qfl[ks] = *(const short8v*)(Ql + ad);
    }
  }

  for (int f = 0; f < TF; ++f) {
    __syncthreads();   // prev PV done with KV union / P
    // ---- stage K [208][64] hi/lo (rows >=196 zero) ----
    for (int id = tid; id < 832; id += 256) {
      const int r = id >> 2, c = id & 3;
      float v[16];
      if (r < 196) {
        const float4* ap = (const float4*)(kg + ((size_t)bh*TN + 1 + f*TP + r)*64 + c*16);
        const float4 a0 = ap[0], a1 = ap[1], a2 = ap[2], a3 = ap[3];
        v[0]=a0.x; v[1]=a0.y; v[2]=a0.z; v[3]=a0.w;
        v[4]=a1.x; v[5]=a1.y; v[6]=a1.z; v[7]=a1.w;
        v[8]=a2.x; v[9]=a2.y; v[10]=a2.z; v[11]=a2.w;
        v[12]=a3.x; v[13]=a3.y; v[14]=a3.z; v[15]=a3.w;
      } else {
        #pragma unroll
        for (int j = 0; j < 16; ++j) v[j] = 0.f;
      }
      u32 hw[8], lw[8];
      #pragma unroll
      for (int j = 0; j < 8; ++j) split2(v[2*j], v[2*j+1], hw[j], lw[j]);
      const int rb = r*64, x = r & 7;
      *(uint4*)(KVh + rb + (((2*c)   ^ x)<<3)) = make_uint4(hw[0],hw[1],hw[2],hw[3]);
      *(uint4*)(KVh + rb + (((2*c+1) ^ x)<<3)) = make_uint4(hw[4],hw[5],hw[6],hw[7]);
      *(uint4*)(KVl + rb + (((2*c)   ^ x)<<3)) = make_uint4(lw[0],lw[1],lw[2],lw[3]);
      *(uint4*)(KVl + rb + (((2*c+1) ^ x)<<3)) = make_uint4(lw[4],lw[5],lw[6],lw[7]);
    }
    __syncthreads();

    // ---- S = Q*K^T : 13 frags (208 key rows) per wave ----
    float4v acc[13];
    #pragma unroll
    for (int t = 0; t < 13; ++t) acc[t] = (float4v){0.f,0.f,0.f,0.f};
    #pragma unroll
    for (int ks = 0; ks < 2; ++ks) {
      #pragma unroll
      for (int t = 0; t < 13; ++t) {
        const int ad = (t*16 + l15)*64 + (((ks*4 + lg4) ^ xk) << 3);
        const short8v kh_ = *(const short8v*)(KVh + ad);
        const short8v kl_ = *(const short8v*)(KVl + ad);
        acc[t] = __builtin_amdgcn_mfma_f32_16x16x32_bf16(qfh[ks], kh_, acc[t], 0, 0, 0);
        acc[t] = __builtin_amdgcn_mfma_f32_16x16x32_bf16(qfh[ks], kl_, acc[t], 0, 0, 0);
        acc[t] = __builtin_amdgcn_mfma_f32_16x16x32_bf16(qfl[ks], kh_, acc[t], 0, 0, 0);
      }
    }

    // ---- softmax over 196 keys per q-row (16-lane shfl groups) + P write ----
    const bool v12 = l15 < 4;   // tile 12 covers n=192..207; valid only n<196
    #pragma unroll
    for (int reg = 0; reg < 4; ++reg) {
      float m = -1e30f;
      #pragma unroll
      for (int t = 0; t < 12; ++t) m = fmaxf(m, acc[t][reg]);
      if (v12) m = fmaxf(m, acc[12][reg]);
      m = fmaxf(m, __shfl_xor(m, 1));
      m = fmaxf(m, __shfl_xor(m, 2));
      m = fmaxf(m, __shfl_xor(m, 4));
      m = fmaxf(m, __shfl_xor(m, 8));
      float sum = 0.f;
      #pragma unroll
      for (int t = 0; t < 13; ++t) {
        if (t < 12 || v12) {
          const float e = __expf(acc[t][reg] - m);
          acc[t][reg] = e; sum += e;
        }
      }
      sum += __shfl_xor(sum, 1);
      sum += __shfl_xor(sum, 2);
      sum += __shfl_xor(sum, 4);
      sum += __shfl_xor(sum, 8);
      const float rl = 1.f / sum;
      const int q = wv*16 + lg4*4 + reg;
      const int qb = q*256, xq = (lg4*4 + reg) & 7;
      #pragma unroll
      for (int t = 0; t < 13; ++t) {
        if (t < 12 || v12) {
          const float p = acc[t][reg] * rl;
          const u16 hi = f2bf(p);
          const u16 lo = f2bf(p - bf2f(hi));
          const int n = t*16 + l15;
          const int ad = qb + (((n>>3) ^ xq)<<3) + (n&7);
          Ph[ad] = hi; Pl[ad] = lo;
        }
      }
    }
    __syncthreads();   // all waves done reading K; P complete

    // ---- stage V^T [64][256] hi/lo into KV union (cols >=196 zero) ----
    for (int id = tid; id < 1792; id += 256) {
      const int np = id >> 4, c = id & 15;
      const int n = 2*np;
      float va[4] = {0.f,0.f,0.f,0.f}, vb[4] = {0.f,0.f,0.f,0.f};
      if (n < 196) {
        const float4 r0 = *(const float4*)(vg + ((size_t)bh*TN + 1 + f*TP + n)*64 + c*4);
        const float4 r1 = *(const float4*)(vg + ((size_t)bh*TN + 1 + f*TP + n + 1)*64 + c*4);
        va[0]=r0.x; va[1]=r0.y; va[2]=r0.z; va[3]=r0.w;
        vb[0]=r1.x; vb[1]=r1.y; vb[2]=r1.z; vb[3]=r1.w;
      }
      #pragma unroll
      for (int d4 = 0; d4 < 4; ++d4) {
        const int d = c*4 + d4;
        u32 hw, lw; split2(va[d4], vb[d4], hw, lw);
        const int ad = d*256 + (((n>>3) ^ (d&7))<<3) + (n&7);
        *(u32*)(KVh + ad) = hw;
        *(u32*)(KVl + ad) = lw;
      }
    }
    __syncthreads();

    // ---- O = P * V^T : 4 d-tiles per wave, K=224 (7 ksteps) ----
    float4v ao[4];
    #pragma unroll
    for (int dt = 0; dt < 4; ++dt) ao[dt] = (float4v){0.f,0.f,0.f,0.f};
    #pragma unroll
    for (int ks = 0; ks < 7; ++ks) {
      const int aad = (wv*16 + l15)*256 + (((ks*4 + lg4) ^ xk) << 3);
      const short8v pah = *(const short8v*)(Ph + aad);
      const short8v pal = *(const short8v*)(Pl + aad);
      #pragma unroll
      for (int dt = 0; dt < 4; ++dt) {
        const int bad = (dt*16 + l15)*256 + (((ks*4 + lg4) ^ xk) << 3);
        const short8v vh_ = *(const short8v*)(KVh + bad);
        const short8v vl_ = *(const short8v*)(KVl + bad);
        ao[dt] = __builtin_amdgcn_mfma_f32_16x16x32_bf16(pah, vh_, ao[dt], 0, 0, 0);
        ao[dt] = __builtin_amdgcn_mfma_f32_16x16x32_bf16(pah, vl_, ao[dt], 0, 0, 0);
        ao[dt] = __builtin_amdgcn_mfma_f32_16x16x32_bf16(pal, vh_, ao[dt], 0, 0, 0);
      }
    }

    // ---- store O to xt (16-lane-contiguous fp32) ----
    #pragma unroll
    for (int dt = 0; dt < 4; ++dt) {
      #pragma unroll
      for (int reg = 0; reg < 4; ++reg) {
        const int sg = qbase + wv*16 + lg4*4 + reg;
        if (sg < TS)
          xt[((size_t)(b*TS + sg)*TF + f)*TC + h*64 + dt*16 + l15] = ao[dt][reg];
      }
    }
  }
}

// ---------------------------------------------------------------------------
// Second stage (unchanged from round 8)
// ---------------------------------------------------------------------------
#define USTRIDE 772

__global__ __launch_bounds__(256) void second_stage(const float* __restrict__ q2,
                                                    const u16* __restrict__ wkvTh,
                                                    const u16* __restrict__ wkvTl,
                                                    const float* __restrict__ xt,
                                                    float* __restrict__ y,
                                                    float* __restrict__ attn2) {
  __shared__ float q2s[768];
  __shared__ float us[12*USTRIDE];
  __shared__ float a2s[96];
  const int tid = threadIdx.x;
  const int bs = blockIdx.x;
  const int b = bs / TS, s = bs - b*TS;

  for (int id = tid; id < 192; id += 256)
    ((float4*)q2s)[id] = ((const float4*)q2)[(size_t)bs*192 + id];
  __syncthreads();

  for (int idx = tid; idx < 9216; idx += 256) {
    const int h = idx / 768, k = idx - h*768;
    const u16* ph = wkvTh + (size_t)(h*64)*768 + k;
    const u16* pl = wkvTl + (size_t)(h*64)*768 + k;
    const float* qq = q2s + h*64;
    float acc = 0.f;
    #pragma unroll 8
    for (int d = 0; d < 64; ++d)
      acc += (bf2f(ph[(size_t)d*768]) + bf2f(pl[(size_t)d*768])) * qq[d];
    us[h*USTRIDE + k] = acc;
  }
  __syncthreads();

  if (tid < 96) {
    const int h = tid >> 3, f = tid & 7;
    const float4* xrow = (const float4*)(xt + (size_t)bs*(TF*TC) + f*TC);
    const float*  urow = us + h*USTRIDE;
    float lgt = 0.f;
    for (int k4 = 0; k4 < 192; ++k4)
      lgt += dot4(xrow[k4], *reinterpret_cast<const float4*>(urow + 4*k4));
    float mx = lgt;
    mx = fmaxf(mx, __shfl_xor(mx, 1, 8));
    mx = fmaxf(mx, __shfl_xor(mx, 2, 8));
    mx = fmaxf(mx, __shfl_xor(mx, 4, 8));
    const float e = __expf(lgt - mx);
    float sum = e;
    sum += __shfl_xor(sum, 1, 8);
    sum += __shfl_xor(sum, 2, 8);
    sum += __shfl_xor(sum, 4, 8);
    const float a = e / sum;
    attn2[((size_t)(b*TH + h)*TS + s)*8 + f] = a;
    a2s[tid] = a;
  }
  __syncthreads();

  const float* xrow0 = xt + (size_t)bs*(TF*TC);
  for (int c = tid; c < 768; c += 256) {
    const int h = c >> 6;
    float o = 0.f;
    #pragma unroll
    for (int f = 0; f < 8; ++f) o += a2s[h*8 + f] * xrow0[f*768 + c];
    y[((size_t)b*TN + 1 + s)*TC + c] = o;
  }
}

// ---------------------------------------------------------------------------
extern "C" void kernel_launch(void* const* d_in, const int* in_sizes, int n_in,
                              void* d_out, int out_size, void* d_ws, size_t ws_size,
                              hipStream_t stream) {
  if (ws_size < WS_NEEDED) return;

  const float* x      = (const float*)d_in[0];
  const float* w_qkv  = (const float*)d_in[1];
  const float* w_q    = (const float*)d_in[2];
  const float* w_kv   = (const float*)d_in[3];
  const float* w_proj = (const float*)d_in[4];
  const float* b_proj = (const float*)d_in[5];

  float* ws = (float*)d_ws;
  float* xt = ws;
  float* qh = xt + XTSZ;
  float* kh = qh + QS;
  float* vh = kh + QS;
  float* q2 = qh;                 // overlay
  float* y  = kh;                 // overlay

  u16* wp = (u16*)(vh + QS);
  u16* wqkvT_h = wp;  wp += 2304*768;
  u16* wqkvT_l = wp;  wp += 2304*768;
  u16* wkvT_h  = wp;  wp += 768*768;
  u16* wkvT_l  = wp;  wp += 768*768;
  u16* wqT_h   = wp;  wp += 768*768;
  u16* wqT_l   = wp;  wp += 768*768;
  u16* wprojT_h = wp; wp += 768*768;
  u16* wprojT_l = wp; wp += 768*768;
  float* clsout = (float*)wp;

  float* outp  = (float*)d_out;
  float* attn2 = outp + YSZ;

  hipFuncSetAttribute(reinterpret_cast<const void*>(space_attn),
                      hipFuncAttributeMaxDynamicSharedMemorySize, SPACE_LDS_BYTES);

  const dim3 blk(256);
  const dim3 tblk(32, 32);
  transpose_split<<<dim3(72, 24), tblk, 0, stream>>>(w_qkv, 2304, wqkvT_h, wqkvT_l);
  transpose_split<<<dim3(24, 24), tblk, 0, stream>>>(w_kv, 1536, wkvT_h, wkvT_l);
  transpose_split<<<dim3(24, 24), tblk, 0, stream>>>(w_q,   768, wqT_h,  wqT_l);
  transpose_split<<<dim3(24, 24), tblk, 0, stream>>>(w_proj,768, wprojT_h, wprojT_l);
  gemm_mfma<0><<<dim3(18, 50), blk, 0, stream>>>(x, nullptr, wqkvT_h, wqkvT_l, qh, kh, vh, nullptr);
  space_attn<<<dim3(25, 48), blk, SPACE_LDS_BYTES, stream>>>(qh, kh, vh, xt);
  cls_attn<<<dim3(48), blk, 0, stream>>>(qh, kh, vh, clsout);
  gemm_mfma<2><<<dim3(6, 49), blk, 0, stream>>>(xt, nullptr, wqT_h, wqT_l, q2, nullptr, nullptr, nullptr);
  second_stage<<<dim3(TB*TS), blk, 0, stream>>>(q2, wkvT_h, wkvT_l, xt, y, attn2);
  gemm_mfma<3><<<dim3(6, 50), blk, 0, stream>>>(y, clsout, wprojT_h, wprojT_l, outp, nullptr, nullptr, b_proj);
}